// Round 14
// baseline (199.217 us; speedup 1.0000x reference)
//
#include <hip/hip_runtime.h>
#include <hip/hip_bf16.h>
#include <math.h>

#define LRELU(v) ((v) > 0.f ? (v) : 0.2f * (v))

typedef __attribute__((ext_vector_type(8))) short bf16x8;
typedef __attribute__((ext_vector_type(4))) float f32x4;

__device__ inline unsigned int f2bf(float f) {
  unsigned int u = __float_as_uint(f);
  return (u + 0x7fffu + ((u >> 16) & 1u)) >> 16;   // RNE
}
__device__ inline float bf_lo(unsigned int u) { return __uint_as_float(u << 16); }
__device__ inline float bf_hi(unsigned int u) { return __uint_as_float(u & 0xffff0000u); }

// ---- W1 transpose + bf16 convert: wt[c*128+k] = bf16(W1[k*128+c]) ---------
__global__ __launch_bounds__(256) void wtrans_k(const float* __restrict__ W,
                                                unsigned short* __restrict__ wt)
{
  int idx = blockIdx.x * 256 + threadIdx.x;   // 16384 elements
  int k = idx >> 7, c = idx & 127;
  wt[c * 128 + k] = (unsigned short)f2bf(W[idx]);
}

// ---- GEMM1 (MFMA bf16): h1 = x @ W1, fused a_s1/a_d1, h1 stored bf16 ------
#define LDA 152
__global__ __launch_bounds__(256) void gemm1_k(
    const float* __restrict__ x, const unsigned short* __restrict__ wt,
    const float* __restrict__ atts, const float* __restrict__ attd,
    unsigned short* __restrict__ h1s, float* __restrict__ as1,
    float* __restrict__ ad1, int N)
{
  __shared__ unsigned short xs[64 * LDA];
  const int t = threadIdx.x;
  const int row0 = blockIdx.x * 64;
  const int lane = t & 63, w = t >> 6;

#pragma unroll
  for (int i = 0; i < 8; ++i) {
    int idx = t + i * 256;
    int r = idx >> 5, kq = idx & 31;
    int rr = row0 + r;
    float4 v = make_float4(0.f, 0.f, 0.f, 0.f);
    if (rr < N) v = *reinterpret_cast<const float4*>(&x[(size_t)rr * 128 + kq * 4]);
    unsigned int p0 = f2bf(v.x) | (f2bf(v.y) << 16);
    unsigned int p1 = f2bf(v.z) | (f2bf(v.w) << 16);
    *reinterpret_cast<uint2*>(&xs[r * LDA + kq * 4]) = make_uint2(p0, p1);
  }
  __syncthreads();

  const int l16 = lane & 15, lhi = lane >> 4;
  const int nb0 = w * 32;
  f32x4 acc[4][2];
#pragma unroll
  for (int m = 0; m < 4; ++m)
#pragma unroll
    for (int n = 0; n < 2; ++n) acc[m][n] = (f32x4){0.f, 0.f, 0.f, 0.f};

#pragma unroll
  for (int ks = 0; ks < 4; ++ks) {
    bf16x8 bf[2];
#pragma unroll
    for (int n = 0; n < 2; ++n) {
      int col = nb0 + n * 16 + l16;
      bf[n] = *reinterpret_cast<const bf16x8*>(&wt[col * 128 + ks * 32 + 8 * lhi]);
    }
#pragma unroll
    for (int m = 0; m < 4; ++m) {
      bf16x8 af = *reinterpret_cast<const bf16x8*>(
          &xs[(m * 16 + l16) * LDA + ks * 32 + 8 * lhi]);
      acc[m][0] = __builtin_amdgcn_mfma_f32_16x16x32_bf16(af, bf[0], acc[m][0], 0, 0, 0);
      acc[m][1] = __builtin_amdgcn_mfma_f32_16x16x32_bf16(af, bf[1], acc[m][1], 0, 0, 0);
    }
  }

#pragma unroll
  for (int n = 0; n < 2; ++n) {
    int col = nb0 + n * 16 + l16;
    float av = atts[col], dv = attd[col];
    int head = w * 2 + n;
#pragma unroll
    for (int m = 0; m < 4; ++m) {
#pragma unroll
      for (int r = 0; r < 4; ++r) {
        int row = row0 + m * 16 + lhi * 4 + r;
        float v = acc[m][n][r];
        float s = v * av, d = v * dv;
        s += __shfl_xor(s, 1); s += __shfl_xor(s, 2);
        s += __shfl_xor(s, 4); s += __shfl_xor(s, 8);
        d += __shfl_xor(d, 1); d += __shfl_xor(d, 2);
        d += __shfl_xor(d, 4); d += __shfl_xor(d, 8);
        if (row < N) {
          h1s[(size_t)row * 128 + col] = (unsigned short)f2bf(v);
          if (l16 == 0) { as1[row * 8 + head] = s; ad1[row * 8 + head] = d; }
        }
      }
    }
  }
}

// ==== Binned CSR build =====================================================
#define NBUK_MAX 256

__global__ __launch_bounds__(256) void bhist_k(const int* __restrict__ ei,
                                               int E, int N,
                                               int* __restrict__ bcnt, int nbuk)
{
  __shared__ int h[NBUK_MAX];
  for (int i = threadIdx.x; i < nbuk; i += 256) h[i] = 0;
  __syncthreads();
  const int Etot = E + N;
  const int base = blockIdx.x * 4096;
#pragma unroll 4
  for (int i = threadIdx.x; i < 4096; i += 256) {
    int e = base + i;
    if (e < Etot) {
      int d = (e < E) ? ei[E + e] : (e - E);
      atomicAdd(&h[d >> 8], 1);
    }
  }
  __syncthreads();
  for (int i = threadIdx.x; i < nbuk; i += 256)
    if (h[i]) atomicAdd(&bcnt[i], h[i]);
}

__global__ __launch_bounds__(256) void bscan_k(const int* __restrict__ bcnt,
                                               int* __restrict__ bbase,
                                               int* __restrict__ bpos, int nbuk)
{
  __shared__ int wsum[4], wtot[4];
  const int t = threadIdx.x, lane = t & 63, w = t >> 6;
  int v = (t < nbuk) ? bcnt[t] : 0;
  int incl = v;
#pragma unroll
  for (int off = 1; off < 64; off <<= 1) {
    int y = __shfl_up(incl, off);
    if (lane >= off) incl += y;
  }
  if (lane == 63) wtot[w] = incl;
  __syncthreads();
  if (t == 0) {
    int a = wtot[0], b = wtot[1], c = wtot[2];
    wsum[0] = 0; wsum[1] = a; wsum[2] = a + b; wsum[3] = a + b + c;
  }
  __syncthreads();
  int ex = wsum[w] + incl - v;
  if (t < nbuk) { bbase[t] = ex; bpos[t] = ex; }
  if (t == nbuk - 1) bbase[nbuk] = ex + v;
}

__global__ __launch_bounds__(256) void bscat_k(const int* __restrict__ ei,
                                               int E, int N,
                                               int* __restrict__ bpos,
                                               unsigned int* __restrict__ stg,
                                               int nbuk)
{
  __shared__ int h[NBUK_MAX], gp[NBUK_MAX], cur[NBUK_MAX];
  for (int i = threadIdx.x; i < nbuk; i += 256) { h[i] = 0; cur[i] = 0; }
  __syncthreads();
  const int Etot = E + N;
  const int base = blockIdx.x * 4096;
  int s[16], d[16];
#pragma unroll
  for (int i = 0; i < 16; ++i) {
    int e = base + i * 256 + threadIdx.x;
    if (e < Etot) {
      if (e < E) { s[i] = ei[e]; d[i] = ei[E + e]; }
      else       { s[i] = d[i] = e - E; }
      atomicAdd(&h[d[i] >> 8], 1);
    } else d[i] = -1;
  }
  __syncthreads();
  for (int i = threadIdx.x; i < nbuk; i += 256)
    gp[i] = h[i] ? atomicAdd(&bpos[i], h[i]) : 0;
  __syncthreads();
#pragma unroll
  for (int i = 0; i < 16; ++i) {
    if (d[i] >= 0) {
      int b = d[i] >> 8;
      int r = atomicAdd(&cur[b], 1);
      stg[gp[b] + r] = ((unsigned int)s[i] << 8) | (unsigned int)(d[i] & 255);
    }
  }
}

#define CCAP 4992
__global__ __launch_bounds__(512) void csr_k(const unsigned int* __restrict__ stg,
                                             const int* __restrict__ bbase,
                                             int* __restrict__ rowptr,
                                             int* __restrict__ col,
                                             int N, int nbuk)
{
  __shared__ int nh[256], nb[257], cur[256], wsum[4];
  __shared__ int cstage[CCAP];
  const int b = blockIdx.x, t = threadIdx.x;
  const int n0 = b << 8;
  const int e0 = bbase[b], e1 = bbase[b + 1], cnt = e1 - e0;
  if (t < 256) { nh[t] = 0; cur[t] = 0; }
  __syncthreads();
  for (int i = t; i < cnt; i += 512)
    atomicAdd(&nh[stg[e0 + i] & 255u], 1);
  __syncthreads();
  if (t < 256) {
    const int lane = t & 63, w = t >> 6;
    int v = nh[t], incl = v;
#pragma unroll
    for (int off = 1; off < 64; off <<= 1) {
      int y = __shfl_up(incl, off);
      if (lane >= off) incl += y;
    }
    if (lane == 63) wsum[w] = incl;
    __syncthreads();
    if (t == 0) {
      int a = wsum[0], bb = wsum[1], c = wsum[2];
      wsum[0] = 0; wsum[1] = a; wsum[2] = a + bb; wsum[3] = a + bb + c;
    }
    __syncthreads();
    int ex = wsum[w] + incl - v;
    nb[t] = ex;
    if (t == 255) nb[256] = ex + v;
  } else {
    __syncthreads();
    __syncthreads();
  }
  __syncthreads();
  const int nnodes = min(256, N - n0);
  for (int i = t; i < nnodes; i += 512) rowptr[n0 + i] = e0 + nb[i];
  if (b == nbuk - 1 && t == 0) rowptr[N] = e1;
  for (int i = t; i < cnt; i += 512) {
    unsigned int sd = stg[e0 + i];
    int li = sd & 255u;
    int p = nb[li] + atomicAdd(&cur[li], 1);
    int sv = (int)(sd >> 8);
    if (p < CCAP) cstage[p] = sv; else col[e0 + p] = sv;
  }
  __syncthreads();
  const int lim = min(cnt, CCAP);
  for (int i = t; i < lim; i += 512) col[e0 + i] = cstage[i];
}

// ---- AGG1F: round-11 edge loop + BN/ELU + FUSED gemm2 (hmid never global) -
// wave/node; edge phase: 2 edges/step x 32 lanes (4ch uint2).
// epilogue: hmid row -> LDS, W2 in LDS, mini-GEMM [1x128]@[128x40] per wave,
// fused as2/ad2 attention dots.
__global__ __launch_bounds__(256) void agg1f_k(
    const unsigned int* __restrict__ h1b, const float* __restrict__ as1,
    const float* __restrict__ ad1, const int* __restrict__ rowptr,
    const int* __restrict__ col, const float* __restrict__ b1,
    const float* __restrict__ gamma, const float* __restrict__ beta,
    const float* __restrict__ mean, const float* __restrict__ var,
    const float* __restrict__ W2, const float* __restrict__ atts2,
    const float* __restrict__ attd2,
    float* __restrict__ h2p, float* __restrict__ as2, float* __restrict__ ad2,
    int N)
{
  __shared__ float w2s[128 * 40];   // 20 KB, layout = W2 (k*40+c)
  __shared__ float hm[4 * 128];     // 2 KB, per-wave hmid row
  const int t = threadIdx.x;
  const int wid = t >> 6, lane = t & 63;
  const int n = blockIdx.x * 4 + wid;
  const bool valid = n < N;

  // stage W2 (coalesced, once per block)
  for (int i = t; i < 128 * 40; i += 256) w2s[i] = W2[i];

  if (valid) {
    const int eh = lane >> 5;          // which edge of the pair
    const int cl = lane & 31;          // channel quad: ch 4cl..4cl+3
    const int h  = cl >> 2;            // head
    const int c0 = cl * 4;
    const float adv = ad1[n * 8 + h];
    float den = 0.f, a0 = 0.f, a1 = 0.f, a2 = 0.f, a3 = 0.f;
    const int jb = rowptr[n], je = rowptr[n + 1];
    for (int j = jb; j < je; j += 8) {
      int s[4]; bool v[4];
#pragma unroll
      for (int q = 0; q < 4; ++q) {
        int idx = j + 2 * q + eh;
        v[q] = idx < je;
        s[q] = col[v[q] ? idx : je - 1];
      }
      float e[4];
#pragma unroll
      for (int q = 0; q < 4; ++q) e[q] = as1[s[q] * 8 + h];
      uint2 u[4];
#pragma unroll
      for (int q = 0; q < 4; ++q)
        u[q] = *reinterpret_cast<const uint2*>(&h1b[s[q] * 64 + cl * 2]);
#pragma unroll
      for (int q = 0; q < 4; ++q) {
        float p = v[q] ? __expf(LRELU(e[q] + adv)) : 0.f;
        den += p;
        a0 += p * bf_lo(u[q].x);
        a1 += p * bf_hi(u[q].x);
        a2 += p * bf_lo(u[q].y);
        a3 += p * bf_hi(u[q].y);
      }
    }
    den += __shfl_xor(den, 32);
    a0 += __shfl_xor(a0, 32);
    a1 += __shfl_xor(a1, 32);
    a2 += __shfl_xor(a2, 32);
    a3 += __shfl_xor(a3, 32);
    if (eh == 0) {
      float r = 1.f / (den + 1e-16f);
      float4 bb = *reinterpret_cast<const float4*>(&b1[c0]);
      float4 mm = *reinterpret_cast<const float4*>(&mean[c0]);
      float4 vv = *reinterpret_cast<const float4*>(&var[c0]);
      float4 gg = *reinterpret_cast<const float4*>(&gamma[c0]);
      float4 be = *reinterpret_cast<const float4*>(&beta[c0]);
      float o0 = a0 * r + bb.x, o1 = a1 * r + bb.y;
      float o2 = a2 * r + bb.z, o3 = a3 * r + bb.w;
      float n0 = (o0 - mm.x) * rsqrtf(vv.x + 1e-5f) * gg.x + be.x;
      float n1 = (o1 - mm.y) * rsqrtf(vv.y + 1e-5f) * gg.y + be.y;
      float n2 = (o2 - mm.z) * rsqrtf(vv.z + 1e-5f) * gg.z + be.z;
      float n3 = (o3 - mm.w) * rsqrtf(vv.w + 1e-5f) * gg.w + be.w;
      float4 o;
      o.x = n0 > 0.f ? n0 : expm1f(n0);
      o.y = n1 > 0.f ? n1 : expm1f(n1);
      o.z = n2 > 0.f ? n2 : expm1f(n2);
      o.w = n3 > 0.f ? n3 : expm1f(n3);
      *reinterpret_cast<float4*>(&hm[wid * 128 + c0]) = o;
    }
  }
  __syncthreads();   // w2s + hm visible

  if (valid) {
    // mini-GEMM: h2p[n][c] = sum_k hm[wid][k] * w2s[k*40+c]
    const int kg = lane >> 3;   // 8 k-groups of 16
    const int cg = lane & 7;    // 8 col-groups of 5
    float acc5[5] = {0.f, 0.f, 0.f, 0.f, 0.f};
#pragma unroll
    for (int j = 0; j < 16; ++j) {
      int k = kg * 16 + j;
      float hmv = hm[wid * 128 + k];
      const float* wr = &w2s[k * 40 + cg * 5];
#pragma unroll
      for (int jc = 0; jc < 5; ++jc) acc5[jc] += hmv * wr[jc];
    }
#pragma unroll
    for (int jc = 0; jc < 5; ++jc) {
      acc5[jc] += __shfl_xor(acc5[jc], 8);
      acc5[jc] += __shfl_xor(acc5[jc], 16);
      acc5[jc] += __shfl_xor(acc5[jc], 32);
    }
    if (kg == 0) {     // lanes 0..7 hold final 5 cols each
      float ps = 0.f, pd = 0.f;
#pragma unroll
      for (int jc = 0; jc < 5; ++jc) {
        int c = cg * 5 + jc;
        h2p[n * 40 + c] = acc5[jc];
        ps += acc5[jc] * atts2[c];
        pd += acc5[jc] * attd2[c];
      }
      ps += __shfl_xor(ps, 1); ps += __shfl_xor(ps, 2); ps += __shfl_xor(ps, 4);
      pd += __shfl_xor(pd, 1); pd += __shfl_xor(pd, 2); pd += __shfl_xor(pd, 4);
      if (cg == 0) { as2[n] = ps; ad2[n] = pd; }
    }
  }
}

// ---- AGG2: 2 edges/step x 32 lanes (2ch float2) — round-11 form -----------
__global__ __launch_bounds__(256) void agg2_k(
    const float* __restrict__ h2p, const float* __restrict__ as2,
    const float* __restrict__ ad2, const int* __restrict__ rowptr,
    const int* __restrict__ col, const float* __restrict__ b2,
    float* __restrict__ out, int N)
{
  const int wid = threadIdx.x >> 6, lane = threadIdx.x & 63;
  const int n = blockIdx.x * 4 + wid;
  if (n >= N) return;
  const int eh = lane >> 5;
  const int cl = lane & 31;          // channel pair 2cl,2cl+1 (cl<20 active)
  const bool actc = cl < 20;
  const int c0 = (actc ? cl : 19) * 2;
  const float adv = ad2[n];
  float den = 0.f, a0 = 0.f, a1 = 0.f;
  const int jb = rowptr[n], je = rowptr[n + 1];
  for (int j = jb; j < je; j += 8) {
    int s[4]; bool v[4];
#pragma unroll
    for (int q = 0; q < 4; ++q) {
      int idx = j + 2 * q + eh;
      v[q] = idx < je;
      s[q] = col[v[q] ? idx : je - 1];
    }
    float e[4];
#pragma unroll
    for (int q = 0; q < 4; ++q) e[q] = as2[s[q]];
    float2 f[4];
#pragma unroll
    for (int q = 0; q < 4; ++q)
      f[q] = *reinterpret_cast<const float2*>(&h2p[s[q] * 40 + c0]);
#pragma unroll
    for (int q = 0; q < 4; ++q) {
      float p = v[q] ? __expf(LRELU(e[q] + adv)) : 0.f;
      den += p;
      a0 += p * f[q].x;
      a1 += p * f[q].y;
    }
  }
  den += __shfl_xor(den, 32);
  a0 += __shfl_xor(a0, 32);
  a1 += __shfl_xor(a1, 32);
  float r = 1.f / (den + 1e-16f);
  float o0 = a0 * r + b2[c0];
  float o1 = a1 * r + b2[c0 + 1];
  const bool act = actc && (eh == 0);
  float mv = act ? fmaxf(o0, o1) : -INFINITY;
#pragma unroll
  for (int off = 1; off < 32; off <<= 1) mv = fmaxf(mv, __shfl_xor(mv, off));
  float ex = act ? (__expf(o0 - mv) + __expf(o1 - mv)) : 0.f;
#pragma unroll
  for (int off = 1; off < 32; off <<= 1) ex += __shfl_xor(ex, off);
  float ls = logf(ex);
  if (act) {
    float2 ov = make_float2(o0 - mv - ls, o1 - mv - ls);
    *reinterpret_cast<float2*>(&out[n * 40 + c0]) = ov;
  }
}

// ---------------------------------------------------------------------------
extern "C" void kernel_launch(void* const* d_in, const int* in_sizes, int n_in,
                              void* d_out, int out_size, void* d_ws,
                              size_t ws_size, hipStream_t stream)
{
  const float* x      = (const float*)d_in[0];
  const int*   ei     = (const int*)d_in[1];
  const float* W1     = (const float*)d_in[2];
  const float* att_s1 = (const float*)d_in[3];
  const float* att_d1 = (const float*)d_in[4];
  const float* b1     = (const float*)d_in[5];
  const float* gamma  = (const float*)d_in[6];
  const float* beta   = (const float*)d_in[7];
  const float* mean   = (const float*)d_in[8];
  const float* var    = (const float*)d_in[9];
  const float* W2     = (const float*)d_in[10];
  const float* att_s2 = (const float*)d_in[11];
  const float* att_d2 = (const float*)d_in[12];
  const float* b2     = (const float*)d_in[13];
  float* out = (float*)d_out;

  const int N = in_sizes[0] / 128;
  const int E = in_sizes[1] / 2;
  const int Etot = E + N;
  const int nbuk = (N + 255) >> 8;
  const int nchunk = (Etot + 4095) / 4096;

  char* ws = (char*)d_ws;
  size_t off = 0;
  auto alloc = [&](size_t bytes) -> void* {
    void* p = ws + off;
    off = (off + bytes + 255) & ~(size_t)255;
    return p;
  };
  unsigned short* h1s = (unsigned short*)alloc((size_t)N * 128 * 2);
  float* as1  = (float*)alloc((size_t)N * 8 * 4);
  float* ad1  = (float*)alloc((size_t)N * 8 * 4);
  float* h2p  = (float*)alloc((size_t)N * 40 * 4);
  float* as2  = (float*)alloc((size_t)N * 4);
  float* ad2  = (float*)alloc((size_t)N * 4);
  int* rowptr = (int*)alloc((size_t)(N + 1) * 4);
  int* col    = (int*)alloc((size_t)Etot * 4);
  unsigned int* stg = (unsigned int*)alloc((size_t)Etot * 4);
  int* bcnt   = (int*)alloc(NBUK_MAX * 4);
  int* bbase  = (int*)alloc((NBUK_MAX + 1) * 4);
  int* bpos   = (int*)alloc(NBUK_MAX * 4);
  unsigned short* wt = (unsigned short*)alloc(16384 * 2);

  hipMemsetAsync(bcnt, 0, NBUK_MAX * 4, stream);

  wtrans_k<<<64, 256, 0, stream>>>(W1, wt);
  gemm1_k<<<(N + 63) / 64, 256, 0, stream>>>(x, wt, att_s1, att_d1,
                                             h1s, as1, ad1, N);
  bhist_k<<<nchunk, 256, 0, stream>>>(ei, E, N, bcnt, nbuk);
  bscan_k<<<1, 256, 0, stream>>>(bcnt, bbase, bpos, nbuk);
  bscat_k<<<nchunk, 256, 0, stream>>>(ei, E, N, bpos, stg, nbuk);
  csr_k<<<nbuk, 512, 0, stream>>>(stg, bbase, rowptr, col, N, nbuk);

  agg1f_k<<<(N + 3) / 4, 256, 0, stream>>>((const unsigned int*)h1s, as1, ad1,
                                           rowptr, col, b1,
                                           gamma, beta, mean, var,
                                           W2, att_s2, att_d2,
                                           h2p, as2, ad2, N);
  agg2_k<<<(N + 3) / 4, 256, 0, stream>>>(h2p, as2, ad2, rowptr, col, b2,
                                          out, N);
}

// Round 15
// 168.038 us; speedup vs baseline: 1.1855x; 1.1855x over previous
//
#include <hip/hip_runtime.h>
#include <hip/hip_bf16.h>
#include <math.h>

#define LRELU(v) ((v) > 0.f ? (v) : 0.2f * (v))

typedef __attribute__((ext_vector_type(8))) short bf16x8;
typedef __attribute__((ext_vector_type(4))) float f32x4;

// Node record layouts:
//  layer1: 288 B = [as1: 8 f32][h1: 128 bf16]   (72 uints; h1 pairs at uint 8)
//  layer2: 176 B = [h2: 40 f32][as2: 1 f32][pad 3]  (stride 44 floats)
#define REC1U 72    // uints per layer-1 record
#define REC1S 144   // ushorts per layer-1 record
#define REC2F 44    // floats per layer-2 record

__device__ inline unsigned int f2bf(float f) {
  unsigned int u = __float_as_uint(f);
  return (u + 0x7fffu + ((u >> 16) & 1u)) >> 16;   // RNE
}
__device__ inline float bf_lo(unsigned int u) { return __uint_as_float(u << 16); }
__device__ inline float bf_hi(unsigned int u) { return __uint_as_float(u & 0xffff0000u); }

// ---- W1 transpose + bf16 convert: wt[c*128+k] = bf16(W1[k*128+c]) ---------
__global__ __launch_bounds__(256) void wtrans_k(const float* __restrict__ W,
                                                unsigned short* __restrict__ wt)
{
  int idx = blockIdx.x * 256 + threadIdx.x;   // 16384 elements
  int k = idx >> 7, c = idx & 127;
  wt[c * 128 + k] = (unsigned short)f2bf(W[idx]);
}

// ---- GEMM1 (MFMA bf16): h1 = x @ W1; h1+as1 packed record, ad1 separate ---
#define LDA 152
__global__ __launch_bounds__(256) void gemm1_k(
    const float* __restrict__ x, const unsigned short* __restrict__ wt,
    const float* __restrict__ atts, const float* __restrict__ attd,
    unsigned short* __restrict__ h1s, float* __restrict__ ad1, int N)
{
  __shared__ unsigned short xs[64 * LDA];
  float* __restrict__ fp1 = (float*)h1s;    // float view of records
  const int t = threadIdx.x;
  const int row0 = blockIdx.x * 64;
  const int lane = t & 63, w = t >> 6;

#pragma unroll
  for (int i = 0; i < 8; ++i) {
    int idx = t + i * 256;
    int r = idx >> 5, kq = idx & 31;
    int rr = row0 + r;
    float4 v = make_float4(0.f, 0.f, 0.f, 0.f);
    if (rr < N) v = *reinterpret_cast<const float4*>(&x[(size_t)rr * 128 + kq * 4]);
    unsigned int p0 = f2bf(v.x) | (f2bf(v.y) << 16);
    unsigned int p1 = f2bf(v.z) | (f2bf(v.w) << 16);
    *reinterpret_cast<uint2*>(&xs[r * LDA + kq * 4]) = make_uint2(p0, p1);
  }
  __syncthreads();

  const int l16 = lane & 15, lhi = lane >> 4;
  const int nb0 = w * 32;
  f32x4 acc[4][2];
#pragma unroll
  for (int m = 0; m < 4; ++m)
#pragma unroll
    for (int n = 0; n < 2; ++n) acc[m][n] = (f32x4){0.f, 0.f, 0.f, 0.f};

#pragma unroll
  for (int ks = 0; ks < 4; ++ks) {
    bf16x8 bf[2];
#pragma unroll
    for (int n = 0; n < 2; ++n) {
      int col = nb0 + n * 16 + l16;
      bf[n] = *reinterpret_cast<const bf16x8*>(&wt[col * 128 + ks * 32 + 8 * lhi]);
    }
#pragma unroll
    for (int m = 0; m < 4; ++m) {
      bf16x8 af = *reinterpret_cast<const bf16x8*>(
          &xs[(m * 16 + l16) * LDA + ks * 32 + 8 * lhi]);
      acc[m][0] = __builtin_amdgcn_mfma_f32_16x16x32_bf16(af, bf[0], acc[m][0], 0, 0, 0);
      acc[m][1] = __builtin_amdgcn_mfma_f32_16x16x32_bf16(af, bf[1], acc[m][1], 0, 0, 0);
    }
  }

#pragma unroll
  for (int n = 0; n < 2; ++n) {
    int col = nb0 + n * 16 + l16;
    float av = atts[col], dv = attd[col];
    int head = w * 2 + n;
#pragma unroll
    for (int m = 0; m < 4; ++m) {
#pragma unroll
      for (int r = 0; r < 4; ++r) {
        int row = row0 + m * 16 + lhi * 4 + r;
        float v = acc[m][n][r];
        float s = v * av, d = v * dv;
        s += __shfl_xor(s, 1); s += __shfl_xor(s, 2);
        s += __shfl_xor(s, 4); s += __shfl_xor(s, 8);
        d += __shfl_xor(d, 1); d += __shfl_xor(d, 2);
        d += __shfl_xor(d, 4); d += __shfl_xor(d, 8);
        if (row < N) {
          h1s[(size_t)row * REC1S + 16 + col] = (unsigned short)f2bf(v);
          if (l16 == 0) {
            fp1[(size_t)row * REC1U + head] = s;   // as1 slot in record
            ad1[row * 8 + head] = d;
          }
        }
      }
    }
  }
}

// ==== Binned CSR build =====================================================
#define NBUK_MAX 256

__global__ __launch_bounds__(256) void bhist_k(const int* __restrict__ ei,
                                               int E, int N,
                                               int* __restrict__ bcnt, int nbuk)
{
  __shared__ int h[NBUK_MAX];
  for (int i = threadIdx.x; i < nbuk; i += 256) h[i] = 0;
  __syncthreads();
  const int Etot = E + N;
  const int base = blockIdx.x * 4096;
#pragma unroll 4
  for (int i = threadIdx.x; i < 4096; i += 256) {
    int e = base + i;
    if (e < Etot) {
      int d = (e < E) ? ei[E + e] : (e - E);
      atomicAdd(&h[d >> 8], 1);
    }
  }
  __syncthreads();
  for (int i = threadIdx.x; i < nbuk; i += 256)
    if (h[i]) atomicAdd(&bcnt[i], h[i]);
}

__global__ __launch_bounds__(256) void bscan_k(const int* __restrict__ bcnt,
                                               int* __restrict__ bbase,
                                               int* __restrict__ bpos, int nbuk)
{
  __shared__ int wsum[4], wtot[4];
  const int t = threadIdx.x, lane = t & 63, w = t >> 6;
  int v = (t < nbuk) ? bcnt[t] : 0;
  int incl = v;
#pragma unroll
  for (int off = 1; off < 64; off <<= 1) {
    int y = __shfl_up(incl, off);
    if (lane >= off) incl += y;
  }
  if (lane == 63) wtot[w] = incl;
  __syncthreads();
  if (t == 0) {
    int a = wtot[0], b = wtot[1], c = wtot[2];
    wsum[0] = 0; wsum[1] = a; wsum[2] = a + b; wsum[3] = a + b + c;
  }
  __syncthreads();
  int ex = wsum[w] + incl - v;
  if (t < nbuk) { bbase[t] = ex; bpos[t] = ex; }
  if (t == nbuk - 1) bbase[nbuk] = ex + v;
}

__global__ __launch_bounds__(256) void bscat_k(const int* __restrict__ ei,
                                               int E, int N,
                                               int* __restrict__ bpos,
                                               unsigned int* __restrict__ stg,
                                               int nbuk)
{
  __shared__ int h[NBUK_MAX], gp[NBUK_MAX], cur[NBUK_MAX];
  for (int i = threadIdx.x; i < nbuk; i += 256) { h[i] = 0; cur[i] = 0; }
  __syncthreads();
  const int Etot = E + N;
  const int base = blockIdx.x * 4096;
  int s[16], d[16];
#pragma unroll
  for (int i = 0; i < 16; ++i) {
    int e = base + i * 256 + threadIdx.x;
    if (e < Etot) {
      if (e < E) { s[i] = ei[e]; d[i] = ei[E + e]; }
      else       { s[i] = d[i] = e - E; }
      atomicAdd(&h[d[i] >> 8], 1);
    } else d[i] = -1;
  }
  __syncthreads();
  for (int i = threadIdx.x; i < nbuk; i += 256)
    gp[i] = h[i] ? atomicAdd(&bpos[i], h[i]) : 0;
  __syncthreads();
#pragma unroll
  for (int i = 0; i < 16; ++i) {
    if (d[i] >= 0) {
      int b = d[i] >> 8;
      int r = atomicAdd(&cur[b], 1);
      stg[gp[b] + r] = ((unsigned int)s[i] << 8) | (unsigned int)(d[i] & 255);
    }
  }
}

#define CCAP 4992
__global__ __launch_bounds__(512) void csr_k(const unsigned int* __restrict__ stg,
                                             const int* __restrict__ bbase,
                                             int* __restrict__ rowptr,
                                             int* __restrict__ col,
                                             int N, int nbuk)
{
  __shared__ int nh[256], nb[257], cur[256], wsum[4];
  __shared__ int cstage[CCAP];
  const int b = blockIdx.x, t = threadIdx.x;
  const int n0 = b << 8;
  const int e0 = bbase[b], e1 = bbase[b + 1], cnt = e1 - e0;
  if (t < 256) { nh[t] = 0; cur[t] = 0; }
  __syncthreads();
  for (int i = t; i < cnt; i += 512)
    atomicAdd(&nh[stg[e0 + i] & 255u], 1);
  __syncthreads();
  if (t < 256) {
    const int lane = t & 63, w = t >> 6;
    int v = nh[t], incl = v;
#pragma unroll
    for (int off = 1; off < 64; off <<= 1) {
      int y = __shfl_up(incl, off);
      if (lane >= off) incl += y;
    }
    if (lane == 63) wsum[w] = incl;
    __syncthreads();
    if (t == 0) {
      int a = wsum[0], bb = wsum[1], c = wsum[2];
      wsum[0] = 0; wsum[1] = a; wsum[2] = a + bb; wsum[3] = a + bb + c;
    }
    __syncthreads();
    int ex = wsum[w] + incl - v;
    nb[t] = ex;
    if (t == 255) nb[256] = ex + v;
  } else {
    __syncthreads();
    __syncthreads();
  }
  __syncthreads();
  const int nnodes = min(256, N - n0);
  for (int i = t; i < nnodes; i += 512) rowptr[n0 + i] = e0 + nb[i];
  if (b == nbuk - 1 && t == 0) rowptr[N] = e1;
  for (int i = t; i < cnt; i += 512) {
    unsigned int sd = stg[e0 + i];
    int li = sd & 255u;
    int p = nb[li] + atomicAdd(&cur[li], 1);
    int sv = (int)(sd >> 8);
    if (p < CCAP) cstage[p] = sv; else col[e0 + p] = sv;
  }
  __syncthreads();
  const int lim = min(cnt, CCAP);
  for (int i = t; i < lim; i += 512) col[e0 + i] = cstage[i];
}

// ---- AGG1: 2 edges/step x 32 lanes (4ch uint2), packed-record gathers -----
__global__ __launch_bounds__(256) void agg1_k(
    const unsigned int* __restrict__ h1u, const float* __restrict__ ad1,
    const int* __restrict__ rowptr, const int* __restrict__ col,
    const float* __restrict__ b1, const float* __restrict__ gamma,
    const float* __restrict__ beta, const float* __restrict__ mean,
    const float* __restrict__ var, float* __restrict__ hmid, int N)
{
  const float* __restrict__ fp1 = (const float*)h1u;
  const int wid = threadIdx.x >> 6, lane = threadIdx.x & 63;
  const int n = blockIdx.x * 4 + wid;
  if (n >= N) return;
  const int eh = lane >> 5;          // which edge of the pair
  const int cl = lane & 31;          // channel quad: ch 4cl..4cl+3
  const int h  = cl >> 2;            // head
  const int c0 = cl * 4;
  const float adv = ad1[n * 8 + h];
  float den = 0.f, a0 = 0.f, a1 = 0.f, a2 = 0.f, a3 = 0.f;
  const int jb = rowptr[n], je = rowptr[n + 1];
  for (int j = jb; j < je; j += 8) {
    int s[4]; bool v[4];
#pragma unroll
    for (int q = 0; q < 4; ++q) {
      int idx = j + 2 * q + eh;
      v[q] = idx < je;
      s[q] = col[v[q] ? idx : je - 1];
    }
    float e[4];
#pragma unroll
    for (int q = 0; q < 4; ++q) e[q] = fp1[s[q] * REC1U + h];
    uint2 u[4];
#pragma unroll
    for (int q = 0; q < 4; ++q)
      u[q] = *reinterpret_cast<const uint2*>(&h1u[s[q] * REC1U + 8 + cl * 2]);
#pragma unroll
    for (int q = 0; q < 4; ++q) {
      float p = v[q] ? __expf(LRELU(e[q] + adv)) : 0.f;
      den += p;
      a0 += p * bf_lo(u[q].x);
      a1 += p * bf_hi(u[q].x);
      a2 += p * bf_lo(u[q].y);
      a3 += p * bf_hi(u[q].y);
    }
  }
  den += __shfl_xor(den, 32);
  a0 += __shfl_xor(a0, 32);
  a1 += __shfl_xor(a1, 32);
  a2 += __shfl_xor(a2, 32);
  a3 += __shfl_xor(a3, 32);
  if (eh == 0) {
    float r = 1.f / (den + 1e-16f);
    float4 bb = *reinterpret_cast<const float4*>(&b1[c0]);
    float4 mm = *reinterpret_cast<const float4*>(&mean[c0]);
    float4 vv = *reinterpret_cast<const float4*>(&var[c0]);
    float4 gg = *reinterpret_cast<const float4*>(&gamma[c0]);
    float4 be = *reinterpret_cast<const float4*>(&beta[c0]);
    float o0 = a0 * r + bb.x, o1 = a1 * r + bb.y;
    float o2 = a2 * r + bb.z, o3 = a3 * r + bb.w;
    float n0 = (o0 - mm.x) * rsqrtf(vv.x + 1e-5f) * gg.x + be.x;
    float n1 = (o1 - mm.y) * rsqrtf(vv.y + 1e-5f) * gg.y + be.y;
    float n2 = (o2 - mm.z) * rsqrtf(vv.z + 1e-5f) * gg.z + be.z;
    float n3 = (o3 - mm.w) * rsqrtf(vv.w + 1e-5f) * gg.w + be.w;
    float4 o;
    o.x = n0 > 0.f ? n0 : expm1f(n0);
    o.y = n1 > 0.f ? n1 : expm1f(n1);
    o.z = n2 > 0.f ? n2 : expm1f(n2);
    o.w = n3 > 0.f ? n3 : expm1f(n3);
    *reinterpret_cast<float4*>(&hmid[n * 128 + c0]) = o;
  }
}

// ---- GEMM2: h2 record = [40 f32 | as2] stride 44; ad2 separate ------------
__global__ __launch_bounds__(256) void gemm2_k(
    const float* __restrict__ hmid, const float* __restrict__ W2,
    const float* __restrict__ atts, const float* __restrict__ attd,
    float* __restrict__ h2f, float* __restrict__ ad2, int N)
{
  __shared__ float hm[128 * 36];
  __shared__ float w2t[40 * 36];
  const int t = threadIdx.x;
  const int n0 = blockIdx.x * 128;
  const int lane = t & 63, w = t >> 6;
  const int ng = lane >> 3, cg = lane & 7;
  const int nloc = w * 32 + ng * 4;

  float acc[4][5];
#pragma unroll
  for (int i = 0; i < 4; ++i)
#pragma unroll
    for (int j = 0; j < 5; ++j) acc[i][j] = 0.f;

  for (int kc = 0; kc < 4; ++kc) {
    __syncthreads();
#pragma unroll
    for (int i = 0; i < 4; ++i) {
      int idx = t + i * 256;
      int r = idx >> 3, kq = idx & 7;
      int rr = n0 + r;
      float4 v = make_float4(0.f, 0.f, 0.f, 0.f);
      if (rr < N)
        v = *reinterpret_cast<const float4*>(&hmid[(size_t)rr * 128 + kc * 32 + kq * 4]);
      *reinterpret_cast<float4*>(&hm[r * 36 + kq * 4]) = v;
    }
#pragma unroll
    for (int i = 0; i < 5; ++i) {
      int flat = t + i * 256;
      int c = flat >> 5, kk = flat & 31;
      w2t[c * 36 + kk] = W2[(size_t)(kc * 32 + kk) * 40 + c];
    }
    __syncthreads();
#pragma unroll
    for (int k4 = 0; k4 < 8; ++k4) {
      float hv[4][4];
#pragma unroll
      for (int i = 0; i < 4; ++i)
        *reinterpret_cast<float4*>(hv[i]) =
            *reinterpret_cast<const float4*>(&hm[(nloc + i) * 36 + k4 * 4]);
      float wv[5][4];
#pragma unroll
      for (int j = 0; j < 5; ++j)
        *reinterpret_cast<float4*>(wv[j]) =
            *reinterpret_cast<const float4*>(&w2t[(cg * 5 + j) * 36 + k4 * 4]);
#pragma unroll
      for (int i = 0; i < 4; ++i)
#pragma unroll
        for (int j = 0; j < 5; ++j)
#pragma unroll
          for (int kk = 0; kk < 4; ++kk)
            acc[i][j] += hv[i][kk] * wv[j][kk];
    }
  }

  float asv[5], adv[5];
#pragma unroll
  for (int j = 0; j < 5; ++j) { asv[j] = atts[cg * 5 + j]; adv[j] = attd[cg * 5 + j]; }
#pragma unroll
  for (int i = 0; i < 4; ++i) {
    int n = n0 + nloc + i;
    if (n >= N) continue;
    float ps = 0.f, pd = 0.f;
#pragma unroll
    for (int j = 0; j < 5; ++j) { ps += acc[i][j] * asv[j]; pd += acc[i][j] * adv[j]; }
#pragma unroll
    for (int off = 1; off < 8; off <<= 1) {
      ps += __shfl_xor(ps, off);
      pd += __shfl_xor(pd, off);
    }
#pragma unroll
    for (int j = 0; j < 5; ++j) h2f[(size_t)n * REC2F + cg * 5 + j] = acc[i][j];
    if (cg == 0) { h2f[(size_t)n * REC2F + 40] = ps; ad2[n] = pd; }
  }
}

// ---- AGG2: 2 edges/step x 32 lanes (2ch float2), packed-record gathers ----
__global__ __launch_bounds__(256) void agg2_k(
    const float* __restrict__ h2f, const float* __restrict__ ad2,
    const int* __restrict__ rowptr, const int* __restrict__ col,
    const float* __restrict__ b2, float* __restrict__ out, int N)
{
  const int wid = threadIdx.x >> 6, lane = threadIdx.x & 63;
  const int n = blockIdx.x * 4 + wid;
  if (n >= N) return;
  const int eh = lane >> 5;
  const int cl = lane & 31;          // channel pair 2cl,2cl+1 (cl<20 active)
  const bool actc = cl < 20;
  const int c0 = (actc ? cl : 19) * 2;
  const float adv = ad2[n];
  float den = 0.f, a0 = 0.f, a1 = 0.f;
  const int jb = rowptr[n], je = rowptr[n + 1];
  for (int j = jb; j < je; j += 8) {
    int s[4]; bool v[4];
#pragma unroll
    for (int q = 0; q < 4; ++q) {
      int idx = j + 2 * q + eh;
      v[q] = idx < je;
      s[q] = col[v[q] ? idx : je - 1];
    }
    float e[4];
#pragma unroll
    for (int q = 0; q < 4; ++q) e[q] = h2f[s[q] * REC2F + 40];
    float2 f[4];
#pragma unroll
    for (int q = 0; q < 4; ++q)
      f[q] = *reinterpret_cast<const float2*>(&h2f[s[q] * REC2F + c0]);
#pragma unroll
    for (int q = 0; q < 4; ++q) {
      float p = v[q] ? __expf(LRELU(e[q] + adv)) : 0.f;
      den += p;
      a0 += p * f[q].x;
      a1 += p * f[q].y;
    }
  }
  den += __shfl_xor(den, 32);
  a0 += __shfl_xor(a0, 32);
  a1 += __shfl_xor(a1, 32);
  float r = 1.f / (den + 1e-16f);
  float o0 = a0 * r + b2[c0];
  float o1 = a1 * r + b2[c0 + 1];
  const bool act = actc && (eh == 0);
  float mv = act ? fmaxf(o0, o1) : -INFINITY;
#pragma unroll
  for (int off = 1; off < 32; off <<= 1) mv = fmaxf(mv, __shfl_xor(mv, off));
  float ex = act ? (__expf(o0 - mv) + __expf(o1 - mv)) : 0.f;
#pragma unroll
  for (int off = 1; off < 32; off <<= 1) ex += __shfl_xor(ex, off);
  float ls = logf(ex);
  if (act) {
    float2 ov = make_float2(o0 - mv - ls, o1 - mv - ls);
    *reinterpret_cast<float2*>(&out[n * 40 + c0]) = ov;
  }
}

// ---------------------------------------------------------------------------
extern "C" void kernel_launch(void* const* d_in, const int* in_sizes, int n_in,
                              void* d_out, int out_size, void* d_ws,
                              size_t ws_size, hipStream_t stream)
{
  const float* x      = (const float*)d_in[0];
  const int*   ei     = (const int*)d_in[1];
  const float* W1     = (const float*)d_in[2];
  const float* att_s1 = (const float*)d_in[3];
  const float* att_d1 = (const float*)d_in[4];
  const float* b1     = (const float*)d_in[5];
  const float* gamma  = (const float*)d_in[6];
  const float* beta   = (const float*)d_in[7];
  const float* mean   = (const float*)d_in[8];
  const float* var    = (const float*)d_in[9];
  const float* W2     = (const float*)d_in[10];
  const float* att_s2 = (const float*)d_in[11];
  const float* att_d2 = (const float*)d_in[12];
  const float* b2     = (const float*)d_in[13];
  float* out = (float*)d_out;

  const int N = in_sizes[0] / 128;
  const int E = in_sizes[1] / 2;
  const int Etot = E + N;
  const int nbuk = (N + 255) >> 8;
  const int nchunk = (Etot + 4095) / 4096;

  char* ws = (char*)d_ws;
  size_t off = 0;
  auto alloc = [&](size_t bytes) -> void* {
    void* p = ws + off;
    off = (off + bytes + 255) & ~(size_t)255;
    return p;
  };
  unsigned short* h1s = (unsigned short*)alloc((size_t)N * REC1S * 2); // 288B rec
  float* ad1  = (float*)alloc((size_t)N * 8 * 4);
  float* hmid = (float*)alloc((size_t)N * 128 * 4);
  int* rowptr = (int*)alloc((size_t)(N + 1) * 4);
  int* col    = (int*)alloc((size_t)Etot * 4);
  unsigned int* stg = (unsigned int*)alloc((size_t)Etot * 4);
  int* bcnt   = (int*)alloc(NBUK_MAX * 4);
  int* bbase  = (int*)alloc((NBUK_MAX + 1) * 4);
  int* bpos   = (int*)alloc(NBUK_MAX * 4);
  unsigned short* wt = (unsigned short*)alloc(16384 * 2);
  // layer-2 record buffer reuses layer-1 record buffer (dead after agg1)
  float* h2f = (float*)h1s;    // N*176B <= N*288B
  float* ad2 = ad1;            // N*4B <= N*32B

  hipMemsetAsync(bcnt, 0, NBUK_MAX * 4, stream);

  wtrans_k<<<64, 256, 0, stream>>>(W1, wt);
  gemm1_k<<<(N + 63) / 64, 256, 0, stream>>>(x, wt, att_s1, att_d1,
                                             h1s, ad1, N);
  bhist_k<<<nchunk, 256, 0, stream>>>(ei, E, N, bcnt, nbuk);
  bscan_k<<<1, 256, 0, stream>>>(bcnt, bbase, bpos, nbuk);
  bscat_k<<<nchunk, 256, 0, stream>>>(ei, E, N, bpos, stg, nbuk);
  csr_k<<<nbuk, 512, 0, stream>>>(stg, bbase, rowptr, col, N, nbuk);

  agg1_k<<<(N + 3) / 4, 256, 0, stream>>>((const unsigned int*)h1s, ad1,
                                          rowptr, col, b1,
                                          gamma, beta, mean, var, hmid, N);
  gemm2_k<<<(N + 127) / 128, 256, 0, stream>>>(hmid, W2, att_s2, att_d2,
                                               h2f, ad2, N);
  agg2_k<<<(N + 3) / 4, 256, 0, stream>>>(h2f, ad2, rowptr, col, b2,
                                          out, N);
}

// Round 16
// 164.227 us; speedup vs baseline: 1.2131x; 1.0232x over previous
//
#include <hip/hip_runtime.h>
#include <hip/hip_bf16.h>
#include <math.h>

#define LRELU(v) ((v) > 0.f ? (v) : 0.2f * (v))

typedef __attribute__((ext_vector_type(8))) short bf16x8;
typedef __attribute__((ext_vector_type(4))) float f32x4;

__device__ inline unsigned int f2bf(float f) {
  unsigned int u = __float_as_uint(f);
  return (u + 0x7fffu + ((u >> 16) & 1u)) >> 16;   // RNE
}
__device__ inline float bf_lo(unsigned int u) { return __uint_as_float(u << 16); }
__device__ inline float bf_hi(unsigned int u) { return __uint_as_float(u & 0xffff0000u); }

#define NBUK_MAX 256

// ---- combined: W1 transpose->bf16 (blocks<64) + bucket histogram ----------
__global__ __launch_bounds__(256) void whist_k(const float* __restrict__ W,
                                               unsigned short* __restrict__ wt,
                                               const int* __restrict__ ei,
                                               int E, int N,
                                               int* __restrict__ bcnt, int nbuk)
{
  // wtrans part: 16384 elements over first 64 blocks
  if (blockIdx.x < 64) {
    int idx = blockIdx.x * 256 + threadIdx.x;
    int k = idx >> 7, c = idx & 127;
    wt[c * 128 + k] = (unsigned short)f2bf(W[idx]);
  }
  // bhist part
  __shared__ int h[NBUK_MAX];
  for (int i = threadIdx.x; i < nbuk; i += 256) h[i] = 0;
  __syncthreads();
  const int Etot = E + N;
  const int base = blockIdx.x * 4096;
#pragma unroll 4
  for (int i = threadIdx.x; i < 4096; i += 256) {
    int e = base + i;
    if (e < Etot) {
      int d = (e < E) ? ei[E + e] : (e - E);
      atomicAdd(&h[d >> 8], 1);
    }
  }
  __syncthreads();
  for (int i = threadIdx.x; i < nbuk; i += 256)
    if (h[i]) atomicAdd(&bcnt[i], h[i]);
}

// ---- GEMM1 (MFMA bf16): h1 = x @ W1, fused a_s1/a_d1, h1 stored bf16 ------
#define LDA 152
__global__ __launch_bounds__(256) void gemm1_k(
    const float* __restrict__ x, const unsigned short* __restrict__ wt,
    const float* __restrict__ atts, const float* __restrict__ attd,
    unsigned short* __restrict__ h1s, float* __restrict__ as1,
    float* __restrict__ ad1, int N)
{
  __shared__ unsigned short xs[64 * LDA];
  const int t = threadIdx.x;
  const int row0 = blockIdx.x * 64;
  const int lane = t & 63, w = t >> 6;

#pragma unroll
  for (int i = 0; i < 8; ++i) {
    int idx = t + i * 256;
    int r = idx >> 5, kq = idx & 31;
    int rr = row0 + r;
    float4 v = make_float4(0.f, 0.f, 0.f, 0.f);
    if (rr < N) v = *reinterpret_cast<const float4*>(&x[(size_t)rr * 128 + kq * 4]);
    unsigned int p0 = f2bf(v.x) | (f2bf(v.y) << 16);
    unsigned int p1 = f2bf(v.z) | (f2bf(v.w) << 16);
    *reinterpret_cast<uint2*>(&xs[r * LDA + kq * 4]) = make_uint2(p0, p1);
  }
  __syncthreads();

  const int l16 = lane & 15, lhi = lane >> 4;
  const int nb0 = w * 32;
  f32x4 acc[4][2];
#pragma unroll
  for (int m = 0; m < 4; ++m)
#pragma unroll
    for (int n = 0; n < 2; ++n) acc[m][n] = (f32x4){0.f, 0.f, 0.f, 0.f};

#pragma unroll
  for (int ks = 0; ks < 4; ++ks) {
    bf16x8 bf[2];
#pragma unroll
    for (int n = 0; n < 2; ++n) {
      int col = nb0 + n * 16 + l16;
      bf[n] = *reinterpret_cast<const bf16x8*>(&wt[col * 128 + ks * 32 + 8 * lhi]);
    }
#pragma unroll
    for (int m = 0; m < 4; ++m) {
      bf16x8 af = *reinterpret_cast<const bf16x8*>(
          &xs[(m * 16 + l16) * LDA + ks * 32 + 8 * lhi]);
      acc[m][0] = __builtin_amdgcn_mfma_f32_16x16x32_bf16(af, bf[0], acc[m][0], 0, 0, 0);
      acc[m][1] = __builtin_amdgcn_mfma_f32_16x16x32_bf16(af, bf[1], acc[m][1], 0, 0, 0);
    }
  }

#pragma unroll
  for (int n = 0; n < 2; ++n) {
    int col = nb0 + n * 16 + l16;
    float av = atts[col], dv = attd[col];
    int head = w * 2 + n;
#pragma unroll
    for (int m = 0; m < 4; ++m) {
#pragma unroll
      for (int r = 0; r < 4; ++r) {
        int row = row0 + m * 16 + lhi * 4 + r;
        float v = acc[m][n][r];
        float s = v * av, d = v * dv;
        s += __shfl_xor(s, 1); s += __shfl_xor(s, 2);
        s += __shfl_xor(s, 4); s += __shfl_xor(s, 8);
        d += __shfl_xor(d, 1); d += __shfl_xor(d, 2);
        d += __shfl_xor(d, 4); d += __shfl_xor(d, 8);
        if (row < N) {
          h1s[(size_t)row * 128 + col] = (unsigned short)f2bf(v);
          if (l16 == 0) { as1[row * 8 + head] = s; ad1[row * 8 + head] = d; }
        }
      }
    }
  }
}

// ---- bscat: in-block bucket prefix + scatter to bucket-contiguous stg -----
__global__ __launch_bounds__(256) void bscat_k(const int* __restrict__ ei,
                                               int E, int N,
                                               const int* __restrict__ bcnt,
                                               int* __restrict__ bcur,
                                               unsigned int* __restrict__ stg,
                                               int nbuk)
{
  __shared__ int bb[NBUK_MAX];     // bucket base (exclusive prefix)
  __shared__ int h[NBUK_MAX], gp[NBUK_MAX], cur[NBUK_MAX];
  __shared__ int wsum[4], wtot[4];
  const int t = threadIdx.x, lane = t & 63, w = t >> 6;
  // in-block exclusive prefix of bcnt
  {
    int v = (t < nbuk) ? bcnt[t] : 0;
    int incl = v;
#pragma unroll
    for (int off = 1; off < 64; off <<= 1) {
      int y = __shfl_up(incl, off);
      if (lane >= off) incl += y;
    }
    if (lane == 63) wtot[w] = incl;
    __syncthreads();
    if (t == 0) {
      int a = wtot[0], b = wtot[1], c = wtot[2];
      wsum[0] = 0; wsum[1] = a; wsum[2] = a + b; wsum[3] = a + b + c;
    }
    __syncthreads();
    if (t < nbuk) bb[t] = wsum[w] + incl - v;
  }
  for (int i = t; i < nbuk; i += 256) { h[i] = 0; cur[i] = 0; }
  __syncthreads();
  const int Etot = E + N;
  const int base = blockIdx.x * 4096;
  int s[16], d[16];
#pragma unroll
  for (int i = 0; i < 16; ++i) {
    int e = base + i * 256 + t;
    if (e < Etot) {
      if (e < E) { s[i] = ei[e]; d[i] = ei[E + e]; }
      else       { s[i] = d[i] = e - E; }
      atomicAdd(&h[d[i] >> 8], 1);
    } else d[i] = -1;
  }
  __syncthreads();
  for (int i = t; i < nbuk; i += 256)
    gp[i] = h[i] ? (bb[i] + atomicAdd(&bcur[i], h[i])) : 0;
  __syncthreads();
#pragma unroll
  for (int i = 0; i < 16; ++i) {
    if (d[i] >= 0) {
      int b = d[i] >> 8;
      int r = atomicAdd(&cur[b], 1);
      stg[gp[b] + r] = ((unsigned int)s[i] << 8) | (unsigned int)(d[i] & 255);
    }
  }
}

// ---- csr: in-block bucket prefix + per-bucket exact CSR -------------------
#define CCAP 4992
__global__ __launch_bounds__(512) void csr_k(const unsigned int* __restrict__ stg,
                                             const int* __restrict__ bcnt,
                                             int* __restrict__ rowptr,
                                             int* __restrict__ col,
                                             int N, int nbuk)
{
  __shared__ int nh[256], nb[257], cur[256], wsum[4], wtot[4];
  __shared__ int cstage[CCAP];
  __shared__ int sE0, sE1;
  const int b = blockIdx.x, t = threadIdx.x;
  const int n0 = b << 8;
  // in-block prefix of bcnt to get e0/e1 for this bucket
  if (t < 256) {
    const int lane = t & 63, w = t >> 6;
    int v = (t < nbuk) ? bcnt[t] : 0;
    int incl = v;
#pragma unroll
    for (int off = 1; off < 64; off <<= 1) {
      int y = __shfl_up(incl, off);
      if (lane >= off) incl += y;
    }
    if (lane == 63) wtot[w] = incl;
    __syncthreads();
    if (t == 0) {
      int a = wtot[0], bb2 = wtot[1], c = wtot[2];
      wsum[0] = 0; wsum[1] = a; wsum[2] = a + bb2; wsum[3] = a + bb2 + c;
    }
    __syncthreads();
    int ex = wsum[w] + incl - v;
    if (t == b) { sE0 = ex; sE1 = ex + v; }
  } else {
    __syncthreads();
    __syncthreads();
  }
  __syncthreads();
  const int e0 = sE0, e1 = sE1, cnt = e1 - e0;

  if (t < 256) { nh[t] = 0; cur[t] = 0; }
  __syncthreads();
  for (int i = t; i < cnt; i += 512)
    atomicAdd(&nh[stg[e0 + i] & 255u], 1);
  __syncthreads();
  if (t < 256) {
    const int lane = t & 63, w = t >> 6;
    int v = nh[t], incl = v;
#pragma unroll
    for (int off = 1; off < 64; off <<= 1) {
      int y = __shfl_up(incl, off);
      if (lane >= off) incl += y;
    }
    if (lane == 63) wsum[w] = incl;
    __syncthreads();
    if (t == 0) {
      int a = wsum[0], bb2 = wsum[1], c = wsum[2];
      wsum[0] = 0; wsum[1] = a; wsum[2] = a + bb2; wsum[3] = a + bb2 + c;
    }
    __syncthreads();
    int ex = wsum[w] + incl - v;
    nb[t] = ex;
    if (t == 255) nb[256] = ex + v;
  } else {
    __syncthreads();
    __syncthreads();
  }
  __syncthreads();
  const int nnodes = min(256, N - n0);
  for (int i = t; i < nnodes; i += 512) rowptr[n0 + i] = e0 + nb[i];
  if (b == nbuk - 1 && t == 0) rowptr[N] = e1;
  for (int i = t; i < cnt; i += 512) {
    unsigned int sd = stg[e0 + i];
    int li = sd & 255u;
    int p = nb[li] + atomicAdd(&cur[li], 1);
    int sv = (int)(sd >> 8);
    if (p < CCAP) cstage[p] = sv; else col[e0 + p] = sv;
  }
  __syncthreads();
  const int lim = min(cnt, CCAP);
  for (int i = t; i < lim; i += 512) col[e0 + i] = cstage[i];
}

// ---- AGG1: 2 edges/step x 32 lanes (4ch via uint2) — round-11 form --------
__global__ __launch_bounds__(256) void agg1_k(
    const unsigned int* __restrict__ h1b, const float* __restrict__ as1,
    const float* __restrict__ ad1, const int* __restrict__ rowptr,
    const int* __restrict__ col, const float* __restrict__ b1,
    const float* __restrict__ gamma, const float* __restrict__ beta,
    const float* __restrict__ mean, const float* __restrict__ var,
    float* __restrict__ hmid, int N)
{
  const int wid = threadIdx.x >> 6, lane = threadIdx.x & 63;
  const int n = blockIdx.x * 4 + wid;
  if (n >= N) return;
  const int eh = lane >> 5;
  const int cl = lane & 31;
  const int h  = cl >> 2;
  const float adv = ad1[n * 8 + h];
  float den = 0.f, a0 = 0.f, a1 = 0.f, a2 = 0.f, a3 = 0.f;
  const int jb = rowptr[n], je = rowptr[n + 1];
  for (int j = jb; j < je; j += 8) {
    int s[4]; bool v[4];
#pragma unroll
    for (int q = 0; q < 4; ++q) {
      int idx = j + 2 * q + eh;
      v[q] = idx < je;
      s[q] = col[v[q] ? idx : je - 1];
    }
    float e[4];
#pragma unroll
    for (int q = 0; q < 4; ++q) e[q] = as1[s[q] * 8 + h];
    uint2 u[4];
#pragma unroll
    for (int q = 0; q < 4; ++q)
      u[q] = *reinterpret_cast<const uint2*>(&h1b[s[q] * 64 + cl * 2]);
#pragma unroll
    for (int q = 0; q < 4; ++q) {
      float p = v[q] ? __expf(LRELU(e[q] + adv)) : 0.f;
      den += p;
      a0 += p * bf_lo(u[q].x);
      a1 += p * bf_hi(u[q].x);
      a2 += p * bf_lo(u[q].y);
      a3 += p * bf_hi(u[q].y);
    }
  }
  den += __shfl_xor(den, 32);
  a0 += __shfl_xor(a0, 32);
  a1 += __shfl_xor(a1, 32);
  a2 += __shfl_xor(a2, 32);
  a3 += __shfl_xor(a3, 32);
  if (eh == 0) {
    const int c0 = cl * 4;
    float r = 1.f / (den + 1e-16f);
    float4 bb = *reinterpret_cast<const float4*>(&b1[c0]);
    float4 mm = *reinterpret_cast<const float4*>(&mean[c0]);
    float4 vv = *reinterpret_cast<const float4*>(&var[c0]);
    float4 gg = *reinterpret_cast<const float4*>(&gamma[c0]);
    float4 be = *reinterpret_cast<const float4*>(&beta[c0]);
    float o0 = a0 * r + bb.x, o1 = a1 * r + bb.y;
    float o2 = a2 * r + bb.z, o3 = a3 * r + bb.w;
    float n0 = (o0 - mm.x) * rsqrtf(vv.x + 1e-5f) * gg.x + be.x;
    float n1 = (o1 - mm.y) * rsqrtf(vv.y + 1e-5f) * gg.y + be.y;
    float n2 = (o2 - mm.z) * rsqrtf(vv.z + 1e-5f) * gg.z + be.z;
    float n3 = (o3 - mm.w) * rsqrtf(vv.w + 1e-5f) * gg.w + be.w;
    float4 o;
    o.x = n0 > 0.f ? n0 : expm1f(n0);
    o.y = n1 > 0.f ? n1 : expm1f(n1);
    o.z = n2 > 0.f ? n2 : expm1f(n2);
    o.w = n3 > 0.f ? n3 : expm1f(n3);
    *reinterpret_cast<float4*>(&hmid[n * 128 + c0]) = o;
  }
}

// ---- GEMM2: h2p = hmid @ W2 (128->40) f32, fused a_s2/a_d2 ----------------
__global__ __launch_bounds__(256) void gemm2_k(
    const float* __restrict__ hmid, const float* __restrict__ W2,
    const float* __restrict__ atts, const float* __restrict__ attd,
    float* __restrict__ h2p, float* __restrict__ as2, float* __restrict__ ad2,
    int N)
{
  __shared__ float hm[128 * 36];
  __shared__ float w2t[40 * 36];
  const int t = threadIdx.x;
  const int n0 = blockIdx.x * 128;
  const int lane = t & 63, w = t >> 6;
  const int ng = lane >> 3, cg = lane & 7;
  const int nloc = w * 32 + ng * 4;

  float acc[4][5];
#pragma unroll
  for (int i = 0; i < 4; ++i)
#pragma unroll
    for (int j = 0; j < 5; ++j) acc[i][j] = 0.f;

  for (int kc = 0; kc < 4; ++kc) {
    __syncthreads();
#pragma unroll
    for (int i = 0; i < 4; ++i) {
      int idx = t + i * 256;
      int r = idx >> 3, kq = idx & 7;
      int rr = n0 + r;
      float4 v = make_float4(0.f, 0.f, 0.f, 0.f);
      if (rr < N)
        v = *reinterpret_cast<const float4*>(&hmid[(size_t)rr * 128 + kc * 32 + kq * 4]);
      *reinterpret_cast<float4*>(&hm[r * 36 + kq * 4]) = v;
    }
#pragma unroll
    for (int i = 0; i < 5; ++i) {
      int flat = t + i * 256;
      int c = flat >> 5, kk = flat & 31;
      w2t[c * 36 + kk] = W2[(size_t)(kc * 32 + kk) * 40 + c];
    }
    __syncthreads();
#pragma unroll
    for (int k4 = 0; k4 < 8; ++k4) {
      float hv[4][4];
#pragma unroll
      for (int i = 0; i < 4; ++i)
        *reinterpret_cast<float4*>(hv[i]) =
            *reinterpret_cast<const float4*>(&hm[(nloc + i) * 36 + k4 * 4]);
      float wv[5][4];
#pragma unroll
      for (int j = 0; j < 5; ++j)
        *reinterpret_cast<float4*>(wv[j]) =
            *reinterpret_cast<const float4*>(&w2t[(cg * 5 + j) * 36 + k4 * 4]);
#pragma unroll
      for (int i = 0; i < 4; ++i)
#pragma unroll
        for (int j = 0; j < 5; ++j)
#pragma unroll
          for (int kk = 0; kk < 4; ++kk)
            acc[i][j] += hv[i][kk] * wv[j][kk];
    }
  }

  float asv[5], adv[5];
#pragma unroll
  for (int j = 0; j < 5; ++j) { asv[j] = atts[cg * 5 + j]; adv[j] = attd[cg * 5 + j]; }
#pragma unroll
  for (int i = 0; i < 4; ++i) {
    int n = n0 + nloc + i;
    if (n >= N) continue;
    float ps = 0.f, pd = 0.f;
#pragma unroll
    for (int j = 0; j < 5; ++j) { ps += acc[i][j] * asv[j]; pd += acc[i][j] * adv[j]; }
#pragma unroll
    for (int off = 1; off < 8; off <<= 1) {
      ps += __shfl_xor(ps, off);
      pd += __shfl_xor(pd, off);
    }
#pragma unroll
    for (int j = 0; j < 5; ++j) h2p[(size_t)n * 40 + cg * 5 + j] = acc[i][j];
    if (cg == 0) { as2[n] = ps; ad2[n] = pd; }
  }
}

// ---- AGG2: 2 edges/step x 32 lanes (2ch via float2) — round-11 form -------
__global__ __launch_bounds__(256) void agg2_k(
    const float* __restrict__ h2p, const float* __restrict__ as2,
    const float* __restrict__ ad2, const int* __restrict__ rowptr,
    const int* __restrict__ col, const float* __restrict__ b2,
    float* __restrict__ out, int N)
{
  const int wid = threadIdx.x >> 6, lane = threadIdx.x & 63;
  const int n = blockIdx.x * 4 + wid;
  if (n >= N) return;
  const int eh = lane >> 5;
  const int cl = lane & 31;
  const bool actc = cl < 20;
  const int c0 = (actc ? cl : 19) * 2;
  const float adv = ad2[n];
  float den = 0.f, a0 = 0.f, a1 = 0.f;
  const int jb = rowptr[n], je = rowptr[n + 1];
  for (int j = jb; j < je; j += 8) {
    int s[4]; bool v[4];
#pragma unroll
    for (int q = 0; q < 4; ++q) {
      int idx = j + 2 * q + eh;
      v[q] = idx < je;
      s[q] = col[v[q] ? idx : je - 1];
    }
    float e[4];
#pragma unroll
    for (int q = 0; q < 4; ++q) e[q] = as2[s[q]];
    float2 f[4];
#pragma unroll
    for (int q = 0; q < 4; ++q)
      f[q] = *reinterpret_cast<const float2*>(&h2p[s[q] * 40 + c0]);
#pragma unroll
    for (int q = 0; q < 4; ++q) {
      float p = v[q] ? __expf(LRELU(e[q] + adv)) : 0.f;
      den += p;
      a0 += p * f[q].x;
      a1 += p * f[q].y;
    }
  }
  den += __shfl_xor(den, 32);
  a0 += __shfl_xor(a0, 32);
  a1 += __shfl_xor(a1, 32);
  float r = 1.f / (den + 1e-16f);
  float o0 = a0 * r + b2[c0];
  float o1 = a1 * r + b2[c0 + 1];
  const bool act = actc && (eh == 0);
  float mv = act ? fmaxf(o0, o1) : -INFINITY;
#pragma unroll
  for (int off = 1; off < 32; off <<= 1) mv = fmaxf(mv, __shfl_xor(mv, off));
  float ex = act ? (__expf(o0 - mv) + __expf(o1 - mv)) : 0.f;
#pragma unroll
  for (int off = 1; off < 32; off <<= 1) ex += __shfl_xor(ex, off);
  float ls = logf(ex);
  if (act) {
    float2 ov = make_float2(o0 - mv - ls, o1 - mv - ls);
    *reinterpret_cast<float2*>(&out[n * 40 + c0]) = ov;
  }
}

// ---------------------------------------------------------------------------
extern "C" void kernel_launch(void* const* d_in, const int* in_sizes, int n_in,
                              void* d_out, int out_size, void* d_ws,
                              size_t ws_size, hipStream_t stream)
{
  const float* x      = (const float*)d_in[0];
  const int*   ei     = (const int*)d_in[1];
  const float* W1     = (const float*)d_in[2];
  const float* att_s1 = (const float*)d_in[3];
  const float* att_d1 = (const float*)d_in[4];
  const float* b1     = (const float*)d_in[5];
  const float* gamma  = (const float*)d_in[6];
  const float* beta   = (const float*)d_in[7];
  const float* mean   = (const float*)d_in[8];
  const float* var    = (const float*)d_in[9];
  const float* W2     = (const float*)d_in[10];
  const float* att_s2 = (const float*)d_in[11];
  const float* att_d2 = (const float*)d_in[12];
  const float* b2     = (const float*)d_in[13];
  float* out = (float*)d_out;

  const int N = in_sizes[0] / 128;
  const int E = in_sizes[1] / 2;
  const int Etot = E + N;
  const int nbuk = (N + 255) >> 8;
  const int nchunk = (Etot + 4095) / 4096;

  char* ws = (char*)d_ws;
  size_t off = 0;
  auto alloc = [&](size_t bytes) -> void* {
    void* p = ws + off;
    off = (off + bytes + 255) & ~(size_t)255;
    return p;
  };
  unsigned short* h1s = (unsigned short*)alloc((size_t)N * 128 * 2);
  float* as1  = (float*)alloc((size_t)N * 8 * 4);
  float* ad1  = (float*)alloc((size_t)N * 8 * 4);
  float* hmid = (float*)alloc((size_t)N * 128 * 4);
  int* rowptr = (int*)alloc((size_t)(N + 1) * 4);
  int* col    = (int*)alloc((size_t)Etot * 4);
  unsigned int* stg = (unsigned int*)alloc((size_t)Etot * 4);
  int* bcnt   = (int*)alloc(NBUK_MAX * 4);
  int* bcur   = (int*)alloc(NBUK_MAX * 4);
  unsigned short* wt = (unsigned short*)alloc(16384 * 2);
  // layer-2 reuses dead layer-1 buffers
  float* h2p = (float*)h1s;   // N*40*4 B <= N*128*2 B
  float* as2 = as1;
  float* ad2 = ad1;

  hipMemsetAsync(bcnt, 0, NBUK_MAX * 4 * 2, stream);  // bcnt + bcur (adjacent)

  whist_k<<<nchunk, 256, 0, stream>>>(W1, wt, ei, E, N, bcnt, nbuk);
  gemm1_k<<<(N + 63) / 64, 256, 0, stream>>>(x, wt, att_s1, att_d1,
                                             h1s, as1, ad1, N);
  bscat_k<<<nchunk, 256, 0, stream>>>(ei, E, N, bcnt, bcur, stg, nbuk);
  csr_k<<<nbuk, 512, 0, stream>>>(stg, bcnt, rowptr, col, N, nbuk);

  agg1_k<<<(N + 3) / 4, 256, 0, stream>>>((const unsigned int*)h1s, as1, ad1,
                                          rowptr, col, b1,
                                          gamma, beta, mean, var, hmid, N);
  gemm2_k<<<(N + 127) / 128, 256, 0, stream>>>(hmid, W2, att_s2, att_d2,
                                               h2p, as2, ad2, N);
  agg2_k<<<(N + 3) / 4, 256, 0, stream>>>(h2p, as2, ad2, rowptr, col, b2,
                                          out, N);
}